// Round 2
// baseline (13684.488 us; speedup 1.0000x reference)
//
#include <hip/hip_runtime.h>

typedef short bf16x8 __attribute__((ext_vector_type(8)));
typedef float f32x4 __attribute__((ext_vector_type(4)));
typedef unsigned short us4 __attribute__((ext_vector_type(4)));

#define MFMA16(a, b, c) __builtin_amdgcn_mfma_f32_16x16x32_bf16(a, b, c, 0, 0, 0)

#define T_ 512
#define C_ 32
#define H_ 256

__device__ __forceinline__ unsigned short f2bf(float f) {
  union { float f; unsigned u; } v; v.f = f;
  return (unsigned short)((v.u + 0x7fffu + ((v.u >> 16) & 1u)) >> 16);
}
__device__ __forceinline__ float fsigmoid(float x) {
  float e = __builtin_amdgcn_exp2f(-1.442695041f * x);
  return __builtin_amdgcn_rcpf(1.0f + e);
}
__device__ __forceinline__ float ftanh(float x) {
  float e = __builtin_amdgcn_exp2f(2.885390082f * x);
  return 1.0f - 2.0f * __builtin_amdgcn_rcpf(e + 1.0f);
}

// ---------- preprocessing: pack W_cat = [Wih | Whh] to bf16, combine biases ----------
__global__ void pack_kernel(
    const float* __restrict__ encWih, const float* __restrict__ encWhh,
    const float* __restrict__ encbih, const float* __restrict__ encbhh,
    const float* __restrict__ decWih, const float* __restrict__ decWhh,
    const float* __restrict__ decbih, const float* __restrict__ decbhh,
    const float* __restrict__ projW, const float* __restrict__ projB,
    unsigned short* __restrict__ encW, unsigned short* __restrict__ decW,
    unsigned short* __restrict__ pW, float* __restrict__ encBias,
    float* __restrict__ decBias, float* __restrict__ pB) {
  int i = blockIdx.x * 256 + threadIdx.x;
  if (i < 768 * 288) {
    int n = i / 288, k = i % 288;
    float ve = (k < 32) ? encWih[n * 32 + k] : encWhh[n * 256 + k - 32];
    float vd = (k < 32) ? decWih[n * 32 + k] : decWhh[n * 256 + k - 32];
    encW[i] = f2bf(ve);
    decW[i] = f2bf(vd);
  }
  if (i < 32 * 256) pW[i] = f2bf(projW[i]);
  if (i < 256) {
    encBias[i]       = encbih[i] + encbhh[i];
    encBias[256 + i] = encbih[256 + i] + encbhh[256 + i];
    encBias[512 + i] = encbih[512 + i];
    encBias[768 + i] = encbhh[512 + i];
    decBias[i]       = decbih[i] + decbhh[i];
    decBias[256 + i] = decbih[256 + i] + decbhh[256 + i];
    decBias[512 + i] = decbih[512 + i];
    decBias[768 + i] = decbhh[512 + i];
  }
  if (i < 32) pB[i] = projB[i];
}

// ---------- weight-stationary GRU: 64 groups x 4 slices ----------
// Block bid: grp = bid&63 (16 samples), sl = bid>>6 (64 hidden cols).
// Weight slice (192 rows x 288) lives in LDS for a whole phase.
// Per step: gather siblings' h-slices (sc1 f32 exchange), 27 MFMA/wave gates,
// gate math, publish own h-slice + release flag. Decoder: proj computed by all
// slices from gathered h (input for next step); slice 0 writes out.
__global__ __launch_bounds__(256, 1) void gru_kernel(
    const float* __restrict__ x,
    const unsigned short* __restrict__ encW,
    const unsigned short* __restrict__ decW,
    const unsigned short* __restrict__ pW,
    const float* __restrict__ encBias,
    const float* __restrict__ decBias,
    const float* __restrict__ pB,
    float* __restrict__ hbuf,      // [2][64][4][1024] f32
    int* __restrict__ flags,      // [64][4][32] int (memset 0 per launch)
    float* __restrict__ out) {
  __shared__ __align__(16) unsigned short wlds[3][64][296];  // 113.7 KB, 2-way-free
  __shared__ __align__(16) unsigned short h_lds[16][264];    // full h, bf16
  __shared__ __align__(16) unsigned short pw_lds[32][264];
  __shared__ __align__(16) unsigned short x_lds[16][40];

  const int tid = (int)threadIdx.x;
  const int wave = tid >> 6, lane = tid & 63;
  const int l15 = lane & 15, l4 = lane >> 4;
  const int ko = l4 * 8;
  const int bid = (int)blockIdx.x;
  const int grp = bid & 63, sl = bid >> 6;
  const int cbase = sl * 64;
  const int gbase = grp * 16;
  const int jl = wave * 16 + l15;   // local col 0..63
  const int j = cbase + jl;         // global hidden col

  for (int i = tid; i < 16 * 264; i += 256) ((unsigned short*)h_lds)[i] = 0;
  for (int i = tid; i < 16 * 40; i += 256) ((unsigned short*)x_lds)[i] = 0;
  for (int i = tid; i < 1024; i += 256) {
    int n = i >> 5, kc = i & 31;
    *(bf16x8*)&pw_lds[n][kc * 8] = *(const bf16x8*)(pW + n * 256 + kc * 8);
  }

  f32x4 hreg = {0.f, 0.f, 0.f, 0.f};
  const float pbias = (wave < 2) ? pB[wave * 16 + l15] : 0.f;
  int* myflag = flags + (grp * 4 + sl) * 32;

  auto spin3 = [&](int need) {
    if (lane == 0 && wave < 3) {
      int sib = wave + (wave >= sl ? 1 : 0);
      const int* fp = flags + (grp * 4 + sib) * 32;
      while (__hip_atomic_load(fp, __ATOMIC_ACQUIRE, __HIP_MEMORY_SCOPE_AGENT) < need)
        __builtin_amdgcn_s_sleep(1);
    }
  };
  auto gather = [&](int sprev) {  // pull siblings' slices of h^{sprev} into h_lds
    const float* hb = hbuf + ((size_t)(sprev & 1) * 64 + grp) * 4 * 1024;
    const int m = tid >> 4, c0 = (tid & 15) * 4;
#pragma unroll
    for (int q = 0; q < 3; ++q) {
      int sp = q + (q >= sl ? 1 : 0);
      const unsigned* src = (const unsigned*)(hb + sp * 1024) + tid * 4;
      unsigned u0 = __hip_atomic_load(src + 0, __ATOMIC_RELAXED, __HIP_MEMORY_SCOPE_AGENT);
      unsigned u1 = __hip_atomic_load(src + 1, __ATOMIC_RELAXED, __HIP_MEMORY_SCOPE_AGENT);
      unsigned u2 = __hip_atomic_load(src + 2, __ATOMIC_RELAXED, __HIP_MEMORY_SCOPE_AGENT);
      unsigned u3 = __hip_atomic_load(src + 3, __ATOMIC_RELAXED, __HIP_MEMORY_SCOPE_AGENT);
      us4 v = {f2bf(__uint_as_float(u0)), f2bf(__uint_as_float(u1)),
               f2bf(__uint_as_float(u2)), f2bf(__uint_as_float(u3))};
      *(us4*)&h_lds[m][sp * 64 + c0] = v;
    }
  };

  for (int phase = 0; phase < 2; ++phase) {
    const unsigned short* W = phase ? decW : encW;
    const float* bias = phase ? decBias : encBias;
    // load this block's weight slice into LDS (rows j, j+256, j+512 for its cols)
    for (int i = tid; i < 3 * 64 * 36; i += 256) {
      int g8 = i / (64 * 36);
      int rem = i - g8 * (64 * 36);
      int jj = rem / 36, kc = rem - (rem / 36) * 36;
      *(bf16x8*)&wlds[g8][jj][kc * 8] =
          *(const bf16x8*)(W + (size_t)(g8 * 256 + cbase + jj) * 288 + kc * 8);
    }
    if (phase == 1)  // decoder start token = zeros
      for (int i = tid; i < 16 * 40; i += 256) ((unsigned short*)x_lds)[i] = 0;
    const float b_r = bias[j], b_z = bias[256 + j];
    const float b_in = bias[512 + j], b_hn = bias[768 + j];

    for (int tt = 0; tt < T_; ++tt) {
      const int s = phase * T_ + tt + 1;  // global step 1..1024, computes h^s
      if (s > 1) {
        spin3(s - 1);
        __syncthreads();
        gather(s - 1);
      }
      if (phase == 0) {  // stage x_t
        for (int i = tid; i < 512; i += 256) {
          int m = i >> 5, c = i & 31;
          x_lds[m][c] = f2bf(x[(size_t)(gbase + m) * (T_ * C_) + tt * C_ + c]);
        }
      }
      __syncthreads();  // S1: h_lds (h^{s-1}) + x_lds/wlds ready

      if (phase == 1 && s > 513) {  // pred_{s-514} = proj(h^{s-1}) -> next input
        if (wave < 2) {
          f32x4 acc = {pbias, pbias, pbias, pbias};
#pragma unroll
          for (int kk = 0; kk < 8; ++kk) {
            bf16x8 ah = *(const bf16x8*)&h_lds[l15][kk * 32 + ko];
            bf16x8 bw = *(const bf16x8*)&pw_lds[wave * 16 + l15][kk * 32 + ko];
            acc = MFMA16(ah, bw, acc);
          }
          const int n = wave * 16 + l15;
#pragma unroll
          for (int r = 0; r < 4; ++r) {
            int m = l4 * 4 + r;
            if (sl == 0)
              out[(size_t)(gbase + m) * (T_ * C_) + (s - 514) * C_ + n] = acc[r];
            x_lds[m][n] = f2bf(acc[r]);
          }
        }
        __syncthreads();  // S1b: x_lds ready
      }

      f32x4 accr  = {b_r, b_r, b_r, b_r};
      f32x4 accz  = {b_z, b_z, b_z, b_z};
      f32x4 accin = {b_in, b_in, b_in, b_in};
      f32x4 acchn = {b_hn, b_hn, b_hn, b_hn};
      {  // x / prev-pred k-chunk (K=32)
        bf16x8 a0 = *(const bf16x8*)&x_lds[l15][ko];
        bf16x8 br = *(const bf16x8*)&wlds[0][jl][ko];
        bf16x8 bz = *(const bf16x8*)&wlds[1][jl][ko];
        bf16x8 bn = *(const bf16x8*)&wlds[2][jl][ko];
        accr  = MFMA16(a0, br, accr);
        accz  = MFMA16(a0, bz, accz);
        accin = MFMA16(a0, bn, accin);
      }
#pragma unroll
      for (int kk = 1; kk <= 8; ++kk) {  // h part (K=256)
        bf16x8 ah = *(const bf16x8*)&h_lds[l15][(kk - 1) * 32 + ko];
        bf16x8 br = *(const bf16x8*)&wlds[0][jl][kk * 32 + ko];
        bf16x8 bz = *(const bf16x8*)&wlds[1][jl][kk * 32 + ko];
        bf16x8 bn = *(const bf16x8*)&wlds[2][jl][kk * 32 + ko];
        accr  = MFMA16(ah, br, accr);
        accz  = MFMA16(ah, bz, accz);
        acchn = MFMA16(ah, bn, acchn);
      }
      __syncthreads();  // S2: all h_lds/x_lds reads done

      float* hb_my = hbuf + (((size_t)(s & 1) * 64 + grp) * 4 + sl) * 1024;
#pragma unroll
      for (int r = 0; r < 4; ++r) {
        float rg = fsigmoid(accr[r]);
        float zg = fsigmoid(accz[r]);
        float ng = ftanh(accin[r] + rg * acchn[r]);
        float hv = zg * (hreg[r] - ng) + ng;
        hreg[r] = hv;
        h_lds[l4 * 4 + r][j] = f2bf(hv);
        __hip_atomic_store((unsigned*)&hb_my[(l4 * 4 + r) * 64 + jl],
                           __float_as_uint(hv), __ATOMIC_RELAXED,
                           __HIP_MEMORY_SCOPE_AGENT);
      }
      __syncthreads();  // S3: barrier drains vmcnt -> stores at coherence point
      if (tid == 0)
        __hip_atomic_store(myflag, s, __ATOMIC_RELEASE, __HIP_MEMORY_SCOPE_AGENT);
    }
  }

  // epilogue: pred_511 = proj(h^{1024})
  spin3(1024);
  __syncthreads();
  gather(1024);
  __syncthreads();
  if (sl == 0 && wave < 2) {
    f32x4 acc = {pbias, pbias, pbias, pbias};
#pragma unroll
    for (int kk = 0; kk < 8; ++kk) {
      bf16x8 ah = *(const bf16x8*)&h_lds[l15][kk * 32 + ko];
      bf16x8 bw = *(const bf16x8*)&pw_lds[wave * 16 + l15][kk * 32 + ko];
      acc = MFMA16(ah, bw, acc);
    }
    const int n = wave * 16 + l15;
#pragma unroll
    for (int r = 0; r < 4; ++r) {
      int m = l4 * 4 + r;
      out[(size_t)(gbase + m) * (T_ * C_) + 511 * C_ + n] = acc[r];
    }
  }
}

extern "C" void kernel_launch(void* const* d_in, const int* in_sizes, int n_in,
                              void* d_out, int out_size, void* d_ws, size_t ws_size,
                              hipStream_t stream) {
  const float* x      = (const float*)d_in[0];
  const float* encWih = (const float*)d_in[1];
  const float* encWhh = (const float*)d_in[2];
  const float* encbih = (const float*)d_in[3];
  const float* encbhh = (const float*)d_in[4];
  const float* decWih = (const float*)d_in[5];
  const float* decWhh = (const float*)d_in[6];
  const float* decbih = (const float*)d_in[7];
  const float* decbhh = (const float*)d_in[8];
  const float* projW  = (const float*)d_in[9];
  const float* projB  = (const float*)d_in[10];

  char* ws = (char*)d_ws;
  unsigned short* encW = (unsigned short*)(ws);             // 442368 B
  unsigned short* decW = (unsigned short*)(ws + 442368);    // 442368 B
  unsigned short* pW   = (unsigned short*)(ws + 884736);    // 16384 B
  float* encBias = (float*)(ws + 901120);                   // 4096 B
  float* decBias = (float*)(ws + 905216);                   // 4096 B
  float* pB      = (float*)(ws + 909312);                   // 128 B
  float* hbuf    = (float*)(ws + (1u << 20));               // 2 MB
  int*   flags   = (int*)(ws + (1u << 20) + 2097152);       // 32 KB

  pack_kernel<<<864, 256, 0, stream>>>(encWih, encWhh, encbih, encbhh,
                                       decWih, decWhh, decbih, decbhh,
                                       projW, projB,
                                       encW, decW, pW, encBias, decBias, pB);
  hipMemsetAsync(flags, 0, 64 * 4 * 32 * sizeof(int), stream);
  gru_kernel<<<256, 256, 0, stream>>>(x, encW, decW, pW, encBias, decBias, pB,
                                      hbuf, flags, (float*)d_out);
}

// Round 3
// 3855.547 us; speedup vs baseline: 3.5493x; 3.5493x over previous
//
#include <hip/hip_runtime.h>

typedef short bf16x8 __attribute__((ext_vector_type(8)));
typedef float f32x4 __attribute__((ext_vector_type(4)));

#define MFMA16(a, b, c) __builtin_amdgcn_mfma_f32_16x16x32_bf16(a, b, c, 0, 0, 0)

#define T_ 512
#define C_ 32
#define H_ 256

__device__ __forceinline__ unsigned short f2bf(float f) {
  union { float f; unsigned u; } v; v.f = f;
  return (unsigned short)((v.u + 0x7fffu + ((v.u >> 16) & 1u)) >> 16);
}
__device__ __forceinline__ float fsigmoid(float x) {
  float e = __builtin_amdgcn_exp2f(-1.442695041f * x);
  return __builtin_amdgcn_rcpf(1.0f + e);
}
__device__ __forceinline__ float ftanh(float x) {
  float e = __builtin_amdgcn_exp2f(2.885390082f * x);
  return 1.0f - 2.0f * __builtin_amdgcn_rcpf(e + 1.0f);
}

// ---------- preprocessing: pack W_cat = [Wih | Whh] to bf16, combine biases ----------
// encW/decW: [768][288] bf16 row-major (cols 0..31 = Wih, 32..287 = Whh)
// bias layout (f32): [0..255]=bih_r+bhh_r, [256..511]=bih_z+bhh_z,
//                    [512..767]=bih_n, [768..1023]=bhh_n
__global__ void pack_kernel(
    const float* __restrict__ encWih, const float* __restrict__ encWhh,
    const float* __restrict__ encbih, const float* __restrict__ encbhh,
    const float* __restrict__ decWih, const float* __restrict__ decWhh,
    const float* __restrict__ decbih, const float* __restrict__ decbhh,
    const float* __restrict__ projW, const float* __restrict__ projB,
    unsigned short* __restrict__ encW, unsigned short* __restrict__ decW,
    unsigned short* __restrict__ pW, float* __restrict__ encBias,
    float* __restrict__ decBias, float* __restrict__ pB) {
  int i = blockIdx.x * 256 + threadIdx.x;
  if (i < 768 * 288) {
    int n = i / 288, k = i % 288;
    float ve = (k < 32) ? encWih[n * 32 + k] : encWhh[n * 256 + k - 32];
    float vd = (k < 32) ? decWih[n * 32 + k] : decWhh[n * 256 + k - 32];
    encW[i] = f2bf(ve);
    decW[i] = f2bf(vd);
  }
  if (i < 32 * 256) pW[i] = f2bf(projW[i]);
  if (i < 256) {
    encBias[i]       = encbih[i] + encbhh[i];
    encBias[256 + i] = encbih[256 + i] + encbhh[256 + i];
    encBias[512 + i] = encbih[512 + i];
    encBias[768 + i] = encbhh[512 + i];
    decBias[i]       = decbih[i] + decbhh[i];
    decBias[256 + i] = decbih[256 + i] + decbhh[256 + i];
    decBias[512 + i] = decbih[512 + i];
    decBias[768 + i] = decbhh[512 + i];
  }
  if (i < 32) pB[i] = projB[i];
}

// ---------- weight-in-register GRU ----------
// 64 blocks x 1024 threads (16 waves, 1 block/CU). Block owns 16 samples.
// Wave w owns hidden cols j = w*16 + l15; holds Whh fragments for gate rows
// {j, j+256, j+512} (24 bf16x8 = 96 VGPR) in registers for a whole phase.
// Wih (48KB) streamed from LDS. h double-buffered in LDS (bf16) + exact f32
// copy in regs (lane owns h[l4*4+r][j]). 1 barrier/step enc, 2/step dec.
__global__ __launch_bounds__(1024) void gru_kernel(
    const float* __restrict__ x,
    const unsigned short* __restrict__ encW,
    const unsigned short* __restrict__ decW,
    const unsigned short* __restrict__ pW,
    const float* __restrict__ encBias,
    const float* __restrict__ decBias,
    const float* __restrict__ pB,
    float* __restrict__ out) {
  __shared__ __align__(16) unsigned short h_lds[2][16][264];  // 16.5 KB
  __shared__ __align__(16) unsigned short xb[2][16][40];      //  2.5 KB
  __shared__ __align__(16) unsigned short wih[3][256][32];    // 48   KB
  __shared__ __align__(16) unsigned short pwl[32][264];       // 16.5 KB

  const int tid = (int)threadIdx.x;
  const int wave = tid >> 6, lane = tid & 63;
  const int l15 = lane & 15, l4 = lane >> 4;
  const int ko = l4 * 8;
  const int gbase = (int)blockIdx.x * 16;
  const int j = wave * 16 + l15;

  for (int i = tid; i < 2 * 16 * 264 / 2; i += 1024) ((unsigned*)h_lds)[i] = 0;
  for (int i = tid; i < 2 * 16 * 40 / 2; i += 1024) ((unsigned*)xb)[i] = 0;
  {
    int n = tid >> 5, slot = tid & 31;
    *(bf16x8*)&pwl[n][slot * 8] = *(const bf16x8*)(pW + n * 256 + slot * 8);
  }

  const float* xLane = x + (size_t)(gbase + (tid >> 5)) * (T_ * C_) + (tid & 31);
  float* outLane = out + (size_t)(gbase + l4 * 4) * (T_ * C_) + wave * 16 + l15;
  const float pbias = (wave < 2) ? pB[wave * 16 + l15] : 0.f;
  f32x4 hreg = {0.f, 0.f, 0.f, 0.f};

  bf16x8 wr[8], wz[8], wn[8];

  auto loadW = [&](const unsigned short* Wp) {
#pragma unroll
    for (int kk = 0; kk < 8; ++kk) {
      wr[kk] = *(const bf16x8*)(Wp + (size_t)j * 288 + 32 + kk * 32 + ko);
      wz[kk] = *(const bf16x8*)(Wp + (size_t)(j + 256) * 288 + 32 + kk * 32 + ko);
      wn[kk] = *(const bf16x8*)(Wp + (size_t)(j + 512) * 288 + 32 + kk * 32 + ko);
    }
    for (int i = tid; i < 3072; i += 1024) {  // Wih -> LDS
      int g = i >> 10, row = (i & 1023) >> 2, kc = (i & 3) * 8;
      *(bf16x8*)&wih[g][row][kc] =
          *(const bf16x8*)(Wp + (size_t)(g * 256 + row) * 288 + kc);
    }
  };

  // ================= encoder =================
  loadW(encW);
  float br = encBias[j], bz = encBias[256 + j];
  float bin = encBias[512 + j], bhn = encBias[768 + j];
  if (tid < 512) xb[0][tid >> 5][tid & 31] = f2bf(xLane[0]);  // stage x_0
  __syncthreads();

#pragma unroll 2
  for (int t = 0; t < T_; ++t) {
    if (t < T_ - 1 && tid < 512)  // stage x_{t+1} into the other buffer
      xb[(t + 1) & 1][tid >> 5][tid & 31] = f2bf(xLane[(size_t)(t + 1) * C_]);

    f32x4 accr = {br, br, br, br}, accz = {bz, bz, bz, bz};
    f32x4 accin = {bin, bin, bin, bin}, acchn = {bhn, bhn, bhn, bhn};
    {
      bf16x8 a0 = *(const bf16x8*)&xb[t & 1][l15][ko];
      accr  = MFMA16(a0, *(const bf16x8*)&wih[0][j][ko], accr);
      accz  = MFMA16(a0, *(const bf16x8*)&wih[1][j][ko], accz);
      accin = MFMA16(a0, *(const bf16x8*)&wih[2][j][ko], accin);
    }
#pragma unroll
    for (int kk = 0; kk < 8; ++kk) {
      bf16x8 ah = *(const bf16x8*)&h_lds[t & 1][l15][kk * 32 + ko];
      accr  = MFMA16(ah, wr[kk], accr);
      accz  = MFMA16(ah, wz[kk], accz);
      acchn = MFMA16(ah, wn[kk], acchn);
    }
#pragma unroll
    for (int r = 0; r < 4; ++r) {
      float rg = fsigmoid(accr[r]);
      float zg = fsigmoid(accz[r]);
      float ng = ftanh(accin[r] + rg * acchn[r]);
      float hv = zg * (hreg[r] - ng) + ng;
      hreg[r] = hv;
      h_lds[(t + 1) & 1][l4 * 4 + r][j] = f2bf(hv);
    }
    __syncthreads();  // h[(t+1)&1] complete; all reads of this step done
  }

  // ================= decoder =================
  loadW(decW);
  br = decBias[j]; bz = decBias[256 + j];
  bin = decBias[512 + j]; bhn = decBias[768 + j];
  if (tid < 320) ((unsigned*)xb)[tid] = 0;  // start token = zeros (xb[0])
  __syncthreads();

#pragma unroll 2
  for (int t = 0; t < T_; ++t) {
    f32x4 accr = {br, br, br, br}, accz = {bz, bz, bz, bz};
    f32x4 accin = {bin, bin, bin, bin}, acchn = {bhn, bhn, bhn, bhn};
    {
      bf16x8 a0 = *(const bf16x8*)&xb[0][l15][ko];
      accr  = MFMA16(a0, *(const bf16x8*)&wih[0][j][ko], accr);
      accz  = MFMA16(a0, *(const bf16x8*)&wih[1][j][ko], accz);
      accin = MFMA16(a0, *(const bf16x8*)&wih[2][j][ko], accin);
    }
#pragma unroll
    for (int kk = 0; kk < 8; ++kk) {
      bf16x8 ah = *(const bf16x8*)&h_lds[t & 1][l15][kk * 32 + ko];
      accr  = MFMA16(ah, wr[kk], accr);
      accz  = MFMA16(ah, wz[kk], accz);
      acchn = MFMA16(ah, wn[kk], acchn);
    }
#pragma unroll
    for (int r = 0; r < 4; ++r) {
      float rg = fsigmoid(accr[r]);
      float zg = fsigmoid(accz[r]);
      float ng = ftanh(accin[r] + rg * acchn[r]);
      float hv = zg * (hreg[r] - ng) + ng;
      hreg[r] = hv;
      h_lds[(t + 1) & 1][l4 * 4 + r][j] = f2bf(hv);
    }
    __syncthreads();  // new h ready; xb[0] reads done

    if (wave < 2) {  // pred_t = proj(h^{t+1}); out + next-step input
      f32x4 pa = {pbias, pbias, pbias, pbias};
#pragma unroll
      for (int kk = 0; kk < 8; ++kk) {
        bf16x8 ah = *(const bf16x8*)&h_lds[(t + 1) & 1][l15][kk * 32 + ko];
        bf16x8 bw = *(const bf16x8*)&pwl[wave * 16 + l15][kk * 32 + ko];
        pa = MFMA16(ah, bw, pa);
      }
#pragma unroll
      for (int r = 0; r < 4; ++r) {
        outLane[(size_t)r * (T_ * C_) + t * C_] = pa[r];
        xb[0][l4 * 4 + r][wave * 16 + l15] = f2bf(pa[r]);
      }
    }
    __syncthreads();  // xb[0] (pred_t) ready for next step
  }
}

extern "C" void kernel_launch(void* const* d_in, const int* in_sizes, int n_in,
                              void* d_out, int out_size, void* d_ws, size_t ws_size,
                              hipStream_t stream) {
  const float* x      = (const float*)d_in[0];
  const float* encWih = (const float*)d_in[1];
  const float* encWhh = (const float*)d_in[2];
  const float* encbih = (const float*)d_in[3];
  const float* encbhh = (const float*)d_in[4];
  const float* decWih = (const float*)d_in[5];
  const float* decWhh = (const float*)d_in[6];
  const float* decbih = (const float*)d_in[7];
  const float* decbhh = (const float*)d_in[8];
  const float* projW  = (const float*)d_in[9];
  const float* projB  = (const float*)d_in[10];

  char* ws = (char*)d_ws;
  unsigned short* encW = (unsigned short*)(ws);             // 442368 B
  unsigned short* decW = (unsigned short*)(ws + 442368);    // 442368 B
  unsigned short* pW   = (unsigned short*)(ws + 884736);    // 16384 B
  float* encBias = (float*)(ws + 901120);                   // 4096 B
  float* decBias = (float*)(ws + 905216);                   // 4096 B
  float* pB      = (float*)(ws + 909312);                   // 128 B

  pack_kernel<<<864, 256, 0, stream>>>(encWih, encWhh, encbih, encbhh,
                                       decWih, decWhh, decbih, decbhh,
                                       projW, projB,
                                       encW, decW, pW, encBias, decBias, pB);
  gru_kernel<<<64, 1024, 0, stream>>>(x, encW, decW, pW, encBias, decBias, pB,
                                      (float*)d_out);
}

// Round 5
// 2484.043 us; speedup vs baseline: 5.5090x; 1.5521x over previous
//
#include <hip/hip_runtime.h>

typedef short bf16x8 __attribute__((ext_vector_type(8)));
typedef float f32x4 __attribute__((ext_vector_type(4)));

#define MFMA16(a, b, c) __builtin_amdgcn_mfma_f32_16x16x32_bf16(a, b, c, 0, 0, 0)

#define T_ 512
#define C_ 32
#define H_ 256

__device__ __forceinline__ unsigned short f2bf(float f) {
  union { float f; unsigned u; } v; v.f = f;
  return (unsigned short)((v.u + 0x7fffu + ((v.u >> 16) & 1u)) >> 16);
}
__device__ __forceinline__ float fsigmoid(float x) {
  float e = __builtin_amdgcn_exp2f(-1.442695041f * x);
  return __builtin_amdgcn_rcpf(1.0f + e);
}
__device__ __forceinline__ float ftanh(float x) {
  float e = __builtin_amdgcn_exp2f(2.885390082f * x);
  return 1.0f - 2.0f * __builtin_amdgcn_rcpf(e + 1.0f);
}

// ---------- preprocessing: pack W_cat = [Wih | Whh] to bf16, combine biases ----------
// encW/decW: [768][288] bf16 row-major (cols 0..31 = Wih, 32..287 = Whh)
// bias layout (f32): [0..255]=bih_r+bhh_r, [256..511]=bih_z+bhh_z,
//                    [512..767]=bih_n, [768..1023]=bhh_n
__global__ void pack_kernel(
    const float* __restrict__ encWih, const float* __restrict__ encWhh,
    const float* __restrict__ encbih, const float* __restrict__ encbhh,
    const float* __restrict__ decWih, const float* __restrict__ decWhh,
    const float* __restrict__ decbih, const float* __restrict__ decbhh,
    const float* __restrict__ projW, const float* __restrict__ projB,
    unsigned short* __restrict__ encW, unsigned short* __restrict__ decW,
    unsigned short* __restrict__ pW, float* __restrict__ encBias,
    float* __restrict__ decBias, float* __restrict__ pB) {
  int i = blockIdx.x * 256 + threadIdx.x;
  if (i < 768 * 288) {
    int n = i / 288, k = i % 288;
    float ve = (k < 32) ? encWih[n * 32 + k] : encWhh[n * 256 + k - 32];
    float vd = (k < 32) ? decWih[n * 32 + k] : decWhh[n * 256 + k - 32];
    encW[i] = f2bf(ve);
    decW[i] = f2bf(vd);
  }
  if (i < 32 * 256) pW[i] = f2bf(projW[i]);
  if (i < 256) {
    encBias[i]       = encbih[i] + encbhh[i];
    encBias[256 + i] = encbih[256 + i] + encbhh[256 + i];
    encBias[512 + i] = encbih[512 + i];
    encBias[768 + i] = encbhh[512 + i];
    decBias[i]       = decbih[i] + decbhh[i];
    decBias[256 + i] = decbih[256 + i] + decbhh[256 + i];
    decBias[512 + i] = decbih[512 + i];
    decBias[768 + i] = decbhh[512 + i];
  }
  if (i < 32) pB[i] = projB[i];
}

// ---------- GRU: weights split registers/LDS, R3-proven sync schedule ----------
// 64 blocks x 1024 threads (16 waves, 1 block/CU). Block owns 16 samples.
// Wave w owns hidden cols j = w*16 + l15. In registers (whole phase):
// Wih(3) + Whh_r(8) + Whh_z(8) + Whh_n k-chunks 0-1 = 21 frags = 84 regs.
// Whh_n k-chunks 2-7 in LDS wnl[6][256][40] (stride 80B = 5x16B odd -> 2
// lanes/bank/phase, conflict-free b128; 16B-aligned rows).
// Encoder: 1 barrier/step. Decoder: compute -> B1 -> proj(waves 0-1) -> B2.
__global__ __launch_bounds__(1024) void gru_kernel(
    const float* __restrict__ x,
    const unsigned short* __restrict__ encW,
    const unsigned short* __restrict__ decW,
    const unsigned short* __restrict__ pW,
    const float* __restrict__ encBias,
    const float* __restrict__ decBias,
    const float* __restrict__ pB,
    float* __restrict__ out) {
  __shared__ __align__(16) unsigned short wnl[6][256][40];    // 120.0 KiB
  __shared__ __align__(16) unsigned short h_lds[2][16][264];  // 16.5 KiB
  __shared__ __align__(16) unsigned short xb[2][16][40];      //  2.5 KiB
  __shared__ __align__(16) unsigned short pwl[32][264];       // 16.5 KiB

  const int tid = (int)threadIdx.x;
  const int wave = tid >> 6, lane = tid & 63;
  const int l15 = lane & 15, l4 = lane >> 4;
  const int ko = l4 * 8;
  const int gbase = (int)blockIdx.x * 16;
  const int j = wave * 16 + l15;

  for (int i = tid; i < 2 * 16 * 264 / 2; i += 1024) ((unsigned*)h_lds)[i] = 0;
  for (int i = tid; i < 2 * 16 * 40 / 2; i += 1024) ((unsigned*)xb)[i] = 0;
  {
    int n = tid >> 5, slot = tid & 31;
    *(bf16x8*)&pwl[n][slot * 8] = *(const bf16x8*)(pW + n * 256 + slot * 8);
  }

  const float* xLane = x + (size_t)(gbase + (tid >> 5)) * (T_ * C_) + (tid & 31);
  float* outLane = out + (size_t)(gbase + l4 * 4) * (T_ * C_) + wave * 16 + l15;
  const float pbias = (wave < 2) ? pB[wave * 16 + l15] : 0.f;
  f32x4 hreg = {0.f, 0.f, 0.f, 0.f};

  bf16x8 wi0, wi1, wi2, wr[8], wz[8], wn2[2];

  auto loadW = [&](const unsigned short* Wp) {
    wi0 = *(const bf16x8*)(Wp + (size_t)j * 288 + ko);
    wi1 = *(const bf16x8*)(Wp + (size_t)(j + 256) * 288 + ko);
    wi2 = *(const bf16x8*)(Wp + (size_t)(j + 512) * 288 + ko);
#pragma unroll
    for (int kk = 0; kk < 8; ++kk) {
      wr[kk] = *(const bf16x8*)(Wp + (size_t)j * 288 + 32 + kk * 32 + ko);
      wz[kk] = *(const bf16x8*)(Wp + (size_t)(j + 256) * 288 + 32 + kk * 32 + ko);
    }
#pragma unroll
    for (int kk = 0; kk < 2; ++kk)
      wn2[kk] = *(const bf16x8*)(Wp + (size_t)(j + 512) * 288 + 32 + kk * 32 + ko);
    // Whh_n k-chunks 2..7 -> LDS (cooperative, conflict-free layout)
    for (int i = tid; i < 6 * 256 * 4; i += 1024) {
      int kc = i >> 10, rem = i & 1023;
      int jj = rem >> 2, kc2 = rem & 3;
      *(bf16x8*)&wnl[kc][jj][kc2 * 8] =
          *(const bf16x8*)(Wp + (size_t)(jj + 512) * 288 + 32 + (kc + 2) * 32 + kc2 * 8);
    }
  };

  // ================= encoder =================
  loadW(encW);
  float br = encBias[j], bz = encBias[256 + j];
  float bin = encBias[512 + j], bhn = encBias[768 + j];
  if (tid < 512) xb[0][tid >> 5][tid & 31] = f2bf(xLane[0]);  // stage x_0
  __syncthreads();

  for (int t = 0; t < T_; ++t) {
    if (t < T_ - 1 && tid < 512)  // stage x_{t+1} into the other buffer
      xb[(t + 1) & 1][tid >> 5][tid & 31] = f2bf(xLane[(size_t)(t + 1) * C_]);

    f32x4 accr = {br, br, br, br}, accz = {bz, bz, bz, bz};
    f32x4 accin = {bin, bin, bin, bin}, acchn = {bhn, bhn, bhn, bhn};
    {  // x chunk (K=32)
      bf16x8 a0 = *(const bf16x8*)&xb[t & 1][l15][ko];
      accr  = MFMA16(a0, wi0, accr);
      accz  = MFMA16(a0, wi1, accz);
      accin = MFMA16(a0, wi2, accin);
    }
#pragma unroll
    for (int kk = 0; kk < 8; ++kk) {  // h part (K=256)
      bf16x8 ah = *(const bf16x8*)&h_lds[t & 1][l15][kk * 32 + ko];
      accr = MFMA16(ah, wr[kk], accr);
      accz = MFMA16(ah, wz[kk], accz);
      bf16x8 wnk = (kk < 2) ? wn2[kk] : *(const bf16x8*)&wnl[kk - 2][j][ko];
      acchn = MFMA16(ah, wnk, acchn);
    }
#pragma unroll
    for (int r = 0; r < 4; ++r) {
      float rg = fsigmoid(accr[r]);
      float zg = fsigmoid(accz[r]);
      float ng = ftanh(accin[r] + rg * acchn[r]);
      float hv = zg * (hreg[r] - ng) + ng;
      hreg[r] = hv;
      h_lds[(t + 1) & 1][l4 * 4 + r][j] = f2bf(hv);
    }
    __syncthreads();  // h[(t+1)&1] + xb[(t+1)&1] visible; step reads done
  }

  // ================= decoder =================
  // h_enc is in h_lds[0] (=h^0_dec) and hreg.
  loadW(decW);
  br = decBias[j]; bz = decBias[256 + j];
  bin = decBias[512 + j]; bhn = decBias[768 + j];
  if (tid < 320) ((unsigned*)xb)[tid] = 0;  // xb[0] = start token zeros
  __syncthreads();

  for (int t = 0; t < T_; ++t) {
    // entry: h_lds[t&1] = h^t, xb[0] = x_t (both barrier-published)
    f32x4 accr = {br, br, br, br}, accz = {bz, bz, bz, bz};
    f32x4 accin = {bin, bin, bin, bin}, acchn = {bhn, bhn, bhn, bhn};
    {  // x chunk
      bf16x8 a0 = *(const bf16x8*)&xb[0][l15][ko];
      accr  = MFMA16(a0, wi0, accr);
      accz  = MFMA16(a0, wi1, accz);
      accin = MFMA16(a0, wi2, accin);
    }
#pragma unroll
    for (int kk = 0; kk < 8; ++kk) {
      bf16x8 ah = *(const bf16x8*)&h_lds[t & 1][l15][kk * 32 + ko];
      accr = MFMA16(ah, wr[kk], accr);
      accz = MFMA16(ah, wz[kk], accz);
      bf16x8 wnk = (kk < 2) ? wn2[kk] : *(const bf16x8*)&wnl[kk - 2][j][ko];
      acchn = MFMA16(ah, wnk, acchn);
    }
#pragma unroll
    for (int r = 0; r < 4; ++r) {
      float rg = fsigmoid(accr[r]);
      float zg = fsigmoid(accz[r]);
      float ng = ftanh(accin[r] + rg * acchn[r]);
      float hv = zg * (hreg[r] - ng) + ng;
      hreg[r] = hv;
      h_lds[(t + 1) & 1][l4 * 4 + r][j] = f2bf(hv);
    }
    __syncthreads();  // B1: h^{t+1} visible; xb[0]/h_lds[t&1] reads done

    if (wave < 2) {  // pred_t = proj(h^{t+1}) -> out + next-step input
      f32x4 pa = {pbias, pbias, pbias, pbias};
#pragma unroll
      for (int kk = 0; kk < 8; ++kk) {
        bf16x8 ah = *(const bf16x8*)&h_lds[(t + 1) & 1][l15][kk * 32 + ko];
        bf16x8 bw = *(const bf16x8*)&pwl[wave * 16 + l15][kk * 32 + ko];
        pa = MFMA16(ah, bw, pa);
      }
#pragma unroll
      for (int r = 0; r < 4; ++r) {
        outLane[(size_t)r * (T_ * C_) + t * C_] = pa[r];
        xb[0][l4 * 4 + r][wave * 16 + l15] = f2bf(pa[r]);  // x_{t+1}
      }
    }
    __syncthreads();  // B2: xb[0] (x_{t+1}) visible to all waves
  }
}

extern "C" void kernel_launch(void* const* d_in, const int* in_sizes, int n_in,
                              void* d_out, int out_size, void* d_ws, size_t ws_size,
                              hipStream_t stream) {
  const float* x      = (const float*)d_in[0];
  const float* encWih = (const float*)d_in[1];
  const float* encWhh = (const float*)d_in[2];
  const float* encbih = (const float*)d_in[3];
  const float* encbhh = (const float*)d_in[4];
  const float* decWih = (const float*)d_in[5];
  const float* decWhh = (const float*)d_in[6];
  const float* decbih = (const float*)d_in[7];
  const float* decbhh = (const float*)d_in[8];
  const float* projW  = (const float*)d_in[9];
  const float* projB  = (const float*)d_in[10];

  char* ws = (char*)d_ws;
  unsigned short* encW = (unsigned short*)(ws);             // 442368 B
  unsigned short* decW = (unsigned short*)(ws + 442368);    // 442368 B
  unsigned short* pW   = (unsigned short*)(ws + 884736);    // 16384 B
  float* encBias = (float*)(ws + 901120);                   // 4096 B
  float* decBias = (float*)(ws + 905216);                   // 4096 B
  float* pB      = (float*)(ws + 909312);                   // 128 B

  pack_kernel<<<864, 256, 0, stream>>>(encWih, encWhh, encbih, encbhh,
                                       decWih, decWhh, decbih, decbhh,
                                       projW, projB,
                                       encW, decW, pW, encBias, decBias, pB);
  gru_kernel<<<64, 1024, 0, stream>>>(x, encW, decW, pW, encBias, decBias, pB,
                                      (float*)d_out);
}